// Round 14
// baseline (3234.726 us; speedup 1.0000x reference)
//
#include <hip/hip_runtime.h>
#include <cstdint>
#include <cstddef>

#define IN_DIM 256
#define HID    512
#define TSTEPS 8
#define ROWS   16
#define NTHR   512     // 128 col-slots x 4 row-groups
#define RPT    4       // rows per thread
#define KC4    96      // OpenBLAS kc=384 boundary in floats/4 (head loops)

// ---- pack: Pf[(k*128+jj)*4 + c] = W[jj+128c][k]  (round-9 proven layout)
__global__ void wpack4(const float* __restrict__ W, float* __restrict__ Pf, int K) {
  __shared__ float tl[32][33];
  const int k0 = blockIdx.x * 32;
  const int j0 = blockIdx.y * 32;
  const int tx = threadIdx.x & 31, ty = threadIdx.x >> 5;
#pragma unroll
  for (int i = 0; i < 32; i += 8)
    tl[ty + i][tx] = W[(size_t)(j0 + ty + i) * K + (k0 + tx)];
  __syncthreads();
  const int c = j0 >> 7;
  const int jjb = j0 & 127;
#pragma unroll
  for (int i = 0; i < 32; i += 8) {
    int k = k0 + ty + i;
    Pf[((size_t)k * 128 + (jjb + tx)) * 4 + c] = tl[tx][ty + i];
  }
}

// ---- dense f32-obs GEMM (layer 1, K=256 single panel) — proven
__device__ __forceinline__ void gemm_obs(const float* __restrict__ obsT,
                                         int rbase, const float4* __restrict__ P,
                                         int j1, float (&A)[RPT][4]) {
#pragma unroll 1
  for (int i4 = 0; i4 < IN_DIM / 4; ++i4) {
    const float4* wp = P + ((size_t)i4 << 9) + j1;
    float4 w0 = wp[0], w1 = wp[128], w2 = wp[256], w3 = wp[384];
#pragma unroll
    for (int r = 0; r < RPT; ++r) {
      float4 o = *reinterpret_cast<const float4*>(obsT + ((rbase + r) << 8) + (i4 << 2));
      float a0 = A[r][0], a1 = A[r][1], a2 = A[r][2], a3 = A[r][3];
      a0 = fmaf(o.x, w0.x, a0); a1 = fmaf(o.x, w0.y, a1); a2 = fmaf(o.x, w0.z, a2); a3 = fmaf(o.x, w0.w, a3);
      a0 = fmaf(o.y, w1.x, a0); a1 = fmaf(o.y, w1.y, a1); a2 = fmaf(o.y, w1.z, a2); a3 = fmaf(o.y, w1.w, a3);
      a0 = fmaf(o.z, w2.x, a0); a1 = fmaf(o.z, w2.y, a1); a2 = fmaf(o.z, w2.z, a2); a3 = fmaf(o.z, w2.w, a3);
      a0 = fmaf(o.w, w3.x, a0); a1 = fmaf(o.w, w3.y, a1); a2 = fmaf(o.w, w3.z, a2); a3 = fmaf(o.w, w3.w, a3);
      A[r][0] = a0; A[r][1] = a1; A[r][2] = a2; A[r][3] = a3;
    }
  }
}

// ---- masked add: apply weight row to the rows whose bit is set in m.
// m is wave-uniform (readfirstlane'd) -> scalar branches, no divergence.
// Adding only to spiked rows == each row consumes exactly its own ascending-k
// chain with __fadd_rn -> bit-identical to per-row lists.
__device__ __forceinline__ void addm(const float4 w, int m, float (&S)[RPT][4]) {
  if (m & 1) {
    S[0][0] = __fadd_rn(S[0][0], w.x); S[0][1] = __fadd_rn(S[0][1], w.y);
    S[0][2] = __fadd_rn(S[0][2], w.z); S[0][3] = __fadd_rn(S[0][3], w.w);
  }
  if (m & 2) {
    S[1][0] = __fadd_rn(S[1][0], w.x); S[1][1] = __fadd_rn(S[1][1], w.y);
    S[1][2] = __fadd_rn(S[1][2], w.z); S[1][3] = __fadd_rn(S[1][3], w.w);
  }
  if (m & 4) {
    S[2][0] = __fadd_rn(S[2][0], w.x); S[2][1] = __fadd_rn(S[2][1], w.y);
    S[2][2] = __fadd_rn(S[2][2], w.z); S[2][3] = __fadd_rn(S[2][3], w.w);
  }
  if (m & 8) {
    S[3][0] = __fadd_rn(S[3][0], w.x); S[3][1] = __fadd_rn(S[3][1], w.y);
    S[3][2] = __fadd_rn(S[3][2], w.z); S[3][3] = __fadd_rn(S[3][3], w.w);
  }
}

// ---- union-sparse panel: entries are u16 (k | rowmask<<12), ascending k.
// One dwordx4 weight fetch serves up to 4 batch rows -> ~0.72x L2 traffic.
__device__ __forceinline__ void panel_u4(const unsigned short* __restrict__ lp, int n,
                                         const float4* __restrict__ P, int j1,
                                         float (&S)[RPT][4]) {
  int i = 0;
#pragma unroll 1
  for (; i + 8 <= n; i += 8) {
    uint4 kw = *reinterpret_cast<const uint4*>(lp + i);
    int s0 = __builtin_amdgcn_readfirstlane((int)kw.x);
    int s1 = __builtin_amdgcn_readfirstlane((int)kw.y);
    int s2 = __builtin_amdgcn_readfirstlane((int)kw.z);
    int s3 = __builtin_amdgcn_readfirstlane((int)kw.w);
    int e0 = s0 & 0xffff, e1 = (s0 >> 16) & 0xffff;
    int e2 = s1 & 0xffff, e3 = (s1 >> 16) & 0xffff;
    int e4 = s2 & 0xffff, e5 = (s2 >> 16) & 0xffff;
    int e6 = s3 & 0xffff, e7 = (s3 >> 16) & 0xffff;
    float4 w0 = P[((e0 & 0xfff) << 7) + j1];
    float4 w1 = P[((e1 & 0xfff) << 7) + j1];
    float4 w2 = P[((e2 & 0xfff) << 7) + j1];
    float4 w3 = P[((e3 & 0xfff) << 7) + j1];
    float4 w4 = P[((e4 & 0xfff) << 7) + j1];
    float4 w5 = P[((e5 & 0xfff) << 7) + j1];
    float4 w6 = P[((e6 & 0xfff) << 7) + j1];
    float4 w7 = P[((e7 & 0xfff) << 7) + j1];
    addm(w0, e0 >> 12, S); addm(w1, e1 >> 12, S);
    addm(w2, e2 >> 12, S); addm(w3, e3 >> 12, S);
    addm(w4, e4 >> 12, S); addm(w5, e5 >> 12, S);
    addm(w6, e6 >> 12, S); addm(w7, e7 >> 12, S);
  }
#pragma unroll 1
  for (; i < n; ++i) {
    int e = __builtin_amdgcn_readfirstlane((int)lp[i]);
    float4 wt = P[((e & 0xfff) << 7) + j1];
    addm(wt, e >> 12, S);
  }
}

// (512,1): no VGPR cap (live set ~150; round-8 showed a 128 cap forces spills).
__launch_bounds__(NTHR, 1)
__global__ void snn_net(const float* __restrict__ obs,
                        const float4* __restrict__ pP1, const float* __restrict__ pb1_,
                        const float4* __restrict__ pP2, const float* __restrict__ pb2_,
                        const float4* __restrict__ pP3, const float* __restrict__ pb3_,
                        const float* __restrict__ paw, const float* __restrict__ pab,
                        const float4* __restrict__ vP1, const float* __restrict__ vb1_,
                        const float4* __restrict__ vP2, const float* __restrict__ vb2_,
                        const float4* __restrict__ vP3, const float* __restrict__ vb3_,
                        const float* __restrict__ vhw, const float* __restrict__ vhb,
                        const float* __restrict__ log_std,
                        float* __restrict__ out, int B) {
  const int bid = blockIdx.x;
  const int xcd = bid & 7;
  const int is_value = xcd >> 2;
  const int tile = (bid >> 3) * 4 + (xcd & 3);
  const float4* P1 = is_value ? vP1 : pP1;  const float* b1 = is_value ? vb1_ : pb1_;
  const float4* P2 = is_value ? vP2 : pP2;  const float* b2 = is_value ? vb2_ : pb2_;
  const float4* P3 = is_value ? vP3 : pP3;  const float* b3 = is_value ? vb3_ : pb3_;
  const float* Wh  = is_value ? vhw : paw;  const float* bh = is_value ? vhb : pab;

  // LDS 32768 B:
  //   start: obsT f32 [0,16K)
  //   loop:  spkA u8 [0,8K); spkB u8 [8K,16K); union lists u16 [16K,20K)
  //          (per group g: 512 entries = 1KB; low panel [0,384), high [384,512))
  //   end:   meanT f32 [0,32K)
  __shared__ __align__(16) unsigned char lraw[32768];
  float* obsT = (float*)lraw;
  float* meanT = (float*)lraw;
  unsigned char* spkA = lraw;
  unsigned char* spkB = lraw + 8192;
  unsigned short* listb = (unsigned short*)(lraw + 16384);

  const int tid = threadIdx.x;
  const int lane = tid & 63;
  const int j1 = tid & 127;
  const int rbase = (tid >> 7) * RPT;   // 0,4,8,12
  const int g = tid >> 7;               // row group 0..3
  const int r0 = tile * ROWS;

  // ---- stage obs tile
  {
    const float4* src = reinterpret_cast<const float4*>(obs + (size_t)r0 * IN_DIM);
    float4* dst = reinterpret_cast<float4*>(obsT);
    for (int e = tid; e < ROWS * IN_DIM / 4; e += NTHR) dst[e] = src[e];
  }
  __syncthreads();

  // ---- layer-1 currents in registers (K=256 single BLAS panel, bias AFTER sum)
  float c1v[RPT][4];
  {
    float Sa[RPT][4];
#pragma unroll
    for (int r = 0; r < RPT; ++r)
#pragma unroll
      for (int c = 0; c < 4; ++c) Sa[r][c] = 0.f;
    gemm_obs(obsT, rbase, P1, j1, Sa);
    const float bb0 = b1[j1], bb1 = b1[j1 + 128], bb2 = b1[j1 + 256], bb3 = b1[j1 + 384];
#pragma unroll
    for (int r = 0; r < RPT; ++r) {
      c1v[r][0] = __fadd_rn(Sa[r][0], bb0);
      c1v[r][1] = __fadd_rn(Sa[r][1], bb1);
      c1v[r][2] = __fadd_rn(Sa[r][2], bb2);
      c1v[r][3] = __fadd_rn(Sa[r][3], bb3);
    }
  }
  __syncthreads();  // obs reads done; spk buffers may alias obsT now

  float m1[RPT][4], m2[RPT][4], m3[RPT][4];
  unsigned cnt32[2] = {0u, 0u};
#pragma unroll
  for (int r = 0; r < RPT; ++r)
#pragma unroll
    for (int c = 0; c < 4; ++c) { m1[r][c] = 0.f; m2[r][c] = 0.f; m3[r][c] = 0.f; }

  const float bias2[4] = { b2[j1], b2[j1 + 128], b2[j1 + 256], b2[j1 + 384] };
  const float bias3[4] = { b3[j1], b3[j1 + 128], b3[j1 + 256], b3[j1 + 384] };

  // ---- union list builder: each wave builds ONE list for its 4 rows (union of
  // spike sets + 4-bit row mask in entry bits 12..15). Sibling waves write
  // identical data (benign WAW, r11/r13-verified). Counts stay in registers.
  auto build_u4 = [&](const unsigned char* __restrict__ sp,
                      int& nlow, int& ntot) {
    unsigned long long b0 = *reinterpret_cast<const unsigned long long*>(sp + ((rbase + 0) << 9) + (lane << 3));
    unsigned long long b1_ = *reinterpret_cast<const unsigned long long*>(sp + ((rbase + 1) << 9) + (lane << 3));
    unsigned long long b2_ = *reinterpret_cast<const unsigned long long*>(sp + ((rbase + 2) << 9) + (lane << 3));
    unsigned long long b3_ = *reinterpret_cast<const unsigned long long*>(sp + ((rbase + 3) << 9) + (lane << 3));
    unsigned long long u = b0 | b1_ | b2_ | b3_;   // bytes are 0/1 -> bit0 = union
    int cnt = __popcll(u);
    int S = cnt;
#pragma unroll
    for (int off = 1; off < 64; off <<= 1) {
      int tv = __shfl_up(S, off);
      if (lane >= off) S += tv;
    }
    ntot = __shfl(S, 63);
    nlow = __shfl(S, 47);           // k < 384 <=> lane < 48
    int excl = S - cnt;
    unsigned short* lrow = listb + (g << 9);
    int pos = (lane < 48) ? excl : (384 + excl - nlow);
#pragma unroll
    for (int b = 0; b < 8; ++b) {
      if ((u >> (8 * b)) & 1ull) {
        int mask = (int)((b0 >> (8 * b)) & 1ull)
                 | ((int)((b1_ >> (8 * b)) & 1ull) << 1)
                 | ((int)((b2_ >> (8 * b)) & 1ull) << 2)
                 | ((int)((b3_ >> (8 * b)) & 1ull) << 3);
        lrow[pos] = (unsigned short)(((lane << 3) + b) | (mask << 12));
        ++pos;
      }
    }
  };

  const unsigned short* lrow = listb + (g << 9);

#pragma unroll 1
  for (int t = 0; t < TSTEPS; ++t) {
    // ---- LIF layer 1 (numpy order) -> spikes u8 -> spkA
#pragma unroll
    for (int r = 0; r < RPT; ++r)
#pragma unroll
      for (int c = 0; c < 4; ++c) {
        m1[r][c] = __fadd_rn(__fmul_rn(0.95f, m1[r][c]), c1v[r][c]);
        bool f = m1[r][c] > 1.0f;
        m1[r][c] = __fsub_rn(m1[r][c], f ? 1.0f : 0.0f);
        spkA[((rbase + r) << 9) + j1 + (c << 7)] = f ? 1 : 0;
      }
    __syncthreads();   // barrier 1: spkA complete; everyone past gemm3(t-1) list reads
    int nlow, ntot;
    build_u4(spkA, nlow, ntot);   // own group's union list -> straight into gemm

    // ---- layer 2: union-sparse panels (kc=384 split), RN(S0+S1)+bias -> spkB
    {
      float S0[RPT][4], S1[RPT][4];
#pragma unroll
      for (int r = 0; r < RPT; ++r)
#pragma unroll
        for (int c = 0; c < 4; ++c) { S0[r][c] = 0.f; S1[r][c] = 0.f; }
      panel_u4(lrow, nlow, P2, j1, S0);
      panel_u4(lrow + 384, ntot - nlow, P2, j1, S1);
#pragma unroll
      for (int r = 0; r < RPT; ++r)
#pragma unroll
        for (int c = 0; c < 4; ++c) {
          float cur = __fadd_rn(__fadd_rn(S0[r][c], S1[r][c]), bias2[c]);
          m2[r][c] = __fadd_rn(__fmul_rn(0.95f, m2[r][c]), cur);
          bool f = m2[r][c] > 1.0f;
          m2[r][c] = __fsub_rn(m2[r][c], f ? 1.0f : 0.0f);
          spkB[((rbase + r) << 9) + j1 + (c << 7)] = f ? 1 : 0;
        }
    }
    __syncthreads();   // barrier 2: spkB complete; all gemm2 list reads done
    build_u4(spkB, nlow, ntot);

    // ---- layer 3: union-sparse panels; packed spike counts
    {
      float S0[RPT][4], S1[RPT][4];
#pragma unroll
      for (int r = 0; r < RPT; ++r)
#pragma unroll
        for (int c = 0; c < 4; ++c) { S0[r][c] = 0.f; S1[r][c] = 0.f; }
      panel_u4(lrow, nlow, P3, j1, S0);
      panel_u4(lrow + 384, ntot - nlow, P3, j1, S1);
#pragma unroll
      for (int r = 0; r < RPT; ++r)
#pragma unroll
        for (int c = 0; c < 4; ++c) {
          float cur = __fadd_rn(__fadd_rn(S0[r][c], S1[r][c]), bias3[c]);
          m3[r][c] = __fadd_rn(__fmul_rn(0.95f, m3[r][c]), cur);
          bool f = m3[r][c] > 1.0f;
          m3[r][c] = __fsub_rn(m3[r][c], f ? 1.0f : 0.0f);
          cnt32[r >> 1] += f ? (1u << (((r & 1) * 4 + c) * 4)) : 0u;
        }
    }
    // next t's barrier 1 fences the list/spkA overwrites
  }
  __syncthreads();

  // ---- mean spikes (count/8 exact)
#pragma unroll
  for (int r = 0; r < RPT; ++r)
#pragma unroll
    for (int c = 0; c < 4; ++c)
      meanT[(rbase + r) * HID + j1 + (c << 7)] =
          (float)((cnt32[r >> 1] >> (((r & 1) * 4 + c) * 4)) & 15u) * 0.125f;
  __syncthreads();

  // ---- heads (BLAS two-panel, kc=384)
  if (is_value == 0) {
    if (tid < ROWS * 6) {
      int r = tid / 6, k = tid % 6;
      const float* wr = Wh + (size_t)k * HID;
      float S0h = 0.f, S1h = 0.f;
      for (int i = 0; i < 4 * KC4; ++i)   S0h = fmaf(meanT[r * HID + i], wr[i], S0h);
      for (int i = 4 * KC4; i < HID; ++i) S1h = fmaf(meanT[r * HID + i], wr[i], S1h);
      out[(size_t)(r0 + r) * 6 + k] = __fadd_rn(__fadd_rn(S0h, S1h), bh[k]);
      out[(size_t)B * 6 + (size_t)(r0 + r) * 6 + k] = log_std[k];
    }
  } else {
    if (tid < ROWS) {
      int r = tid;
      float S0h = 0.f, S1h = 0.f;
      for (int i = 0; i < 4 * KC4; ++i)   S0h = fmaf(meanT[r * HID + i], Wh[i], S0h);
      for (int i = 4 * KC4; i < HID; ++i) S1h = fmaf(meanT[r * HID + i], Wh[i], S1h);
      out[(size_t)B * 12 + (size_t)(r0 + r)] = __fadd_rn(__fadd_rn(S0h, S1h), bh[0]);
    }
  }
}

// ---------------- fallback (round-3 kernel, proven) ----------------
#define NTHRB 512
#define RPTB  8
template<int PITCH4>
__device__ __forceinline__ void gemm_f32(const float* __restrict__ sl, int rbase,
                                         const float4* __restrict__ wra,
                                         const float4* __restrict__ wrb,
                                         int i4begin, int i4end,
                                         float a0[RPTB], float a1[RPTB]) {
  const float4* slv = reinterpret_cast<const float4*>(sl);
  for (int i4 = i4begin; i4 < i4end; ++i4) {
    float4 wa = wra[i4];
    float4 wb = wrb[i4];
#pragma unroll
    for (int r = 0; r < RPTB; ++r) {
      float4 s = slv[(rbase + r) * PITCH4 + i4];
      a0[r] = fmaf(s.w, wa.w, fmaf(s.z, wa.z, fmaf(s.y, wa.y, fmaf(s.x, wa.x, a0[r]))));
      a1[r] = fmaf(s.w, wb.w, fmaf(s.z, wb.z, fmaf(s.y, wb.y, fmaf(s.x, wb.x, a1[r]))));
    }
  }
}

__launch_bounds__(NTHRB, 2)
__global__ void snn_net_base(const float* __restrict__ obs,
                             const float* __restrict__ pW1, const float* __restrict__ pb1_,
                             const float* __restrict__ pW2, const float* __restrict__ pb2_,
                             const float* __restrict__ pW3, const float* __restrict__ pb3_,
                             const float* __restrict__ paw, const float* __restrict__ pab,
                             const float* __restrict__ vW1, const float* __restrict__ vb1_,
                             const float* __restrict__ vW2, const float* __restrict__ vb2_,
                             const float* __restrict__ vW3, const float* __restrict__ vb3_,
                             const float* __restrict__ vhw, const float* __restrict__ vhb,
                             const float* __restrict__ log_std,
                             float* __restrict__ out, int B) {
  const int is_value = blockIdx.y;
  const float* W1 = is_value ? vW1 : pW1;  const float* b1 = is_value ? vb1_ : pb1_;
  const float* W2 = is_value ? vW2 : pW2;  const float* b2 = is_value ? vb2_ : pb2_;
  const float* W3 = is_value ? vW3 : pW3;  const float* b3 = is_value ? vb3_ : pb3_;
  const float* Wh = is_value ? vhw : paw;  const float* bh = is_value ? vhb : pab;

  __shared__ float sl[ROWS * HID];
  const int tid = threadIdx.x;
  const int r0 = blockIdx.x * ROWS;
  const int j1 = tid & 255, j2 = j1 + 256;
  const int rbase = (tid >> 8) * RPTB;

  for (int e = tid; e < ROWS * IN_DIM; e += NTHRB)
    sl[e] = obs[(size_t)r0 * IN_DIM + e];
  __syncthreads();

  float c1a[RPTB], c1b[RPTB];
  {
    float Sa[RPTB], Sb[RPTB];
#pragma unroll
    for (int r = 0; r < RPTB; ++r) { Sa[r] = 0.f; Sb[r] = 0.f; }
    gemm_f32<IN_DIM / 4>(sl, rbase,
        reinterpret_cast<const float4*>(W1 + (size_t)j1 * IN_DIM),
        reinterpret_cast<const float4*>(W1 + (size_t)j2 * IN_DIM),
        0, IN_DIM / 4, Sa, Sb);
    const float ba = b1[j1], bb = b1[j2];
#pragma unroll
    for (int r = 0; r < RPTB; ++r) {
      c1a[r] = __fadd_rn(Sa[r], ba);
      c1b[r] = __fadd_rn(Sb[r], bb);
    }
  }
  __syncthreads();

  float m1a[RPTB], m1b[RPTB], m2a[RPTB], m2b[RPTB], m3a[RPTB], m3b[RPTB];
  float sca[RPTB], scb[RPTB];
#pragma unroll
  for (int r = 0; r < RPTB; ++r) {
    m1a[r] = 0.f; m1b[r] = 0.f; m2a[r] = 0.f; m2b[r] = 0.f;
    m3a[r] = 0.f; m3b[r] = 0.f; sca[r] = 0.f; scb[r] = 0.f;
  }

  const float4* w2a = reinterpret_cast<const float4*>(W2 + (size_t)j1 * HID);
  const float4* w2b = reinterpret_cast<const float4*>(W2 + (size_t)j2 * HID);
  const float4* w3a = reinterpret_cast<const float4*>(W3 + (size_t)j1 * HID);
  const float4* w3b = reinterpret_cast<const float4*>(W3 + (size_t)j2 * HID);
  const float bias2a = b2[j1], bias2b = b2[j2];
  const float bias3a = b3[j1], bias3b = b3[j2];

  for (int t = 0; t < TSTEPS; ++t) {
#pragma unroll
    for (int r = 0; r < RPTB; ++r) {
      m1a[r] = __fadd_rn(__fmul_rn(0.95f, m1a[r]), c1a[r]);
      float sa = (m1a[r] > 1.0f) ? 1.0f : 0.0f;
      m1a[r] = __fsub_rn(m1a[r], sa);
      sl[(rbase + r) * HID + j1] = sa;
      m1b[r] = __fadd_rn(__fmul_rn(0.95f, m1b[r]), c1b[r]);
      float sb = (m1b[r] > 1.0f) ? 1.0f : 0.0f;
      m1b[r] = __fsub_rn(m1b[r], sb);
      sl[(rbase + r) * HID + j2] = sb;
    }
    __syncthreads();

    float S0a[RPTB], S0b[RPTB], S1a[RPTB], S1b[RPTB];
#pragma unroll
    for (int r = 0; r < RPTB; ++r) { S0a[r] = 0.f; S0b[r] = 0.f; S1a[r] = 0.f; S1b[r] = 0.f; }
    gemm_f32<HID / 4>(sl, rbase, w2a, w2b, 0, KC4, S0a, S0b);
    gemm_f32<HID / 4>(sl, rbase, w2a, w2b, KC4, HID / 4, S1a, S1b);
    __syncthreads();
#pragma unroll
    for (int r = 0; r < RPTB; ++r) {
      float cura = __fadd_rn(__fadd_rn(S0a[r], S1a[r]), bias2a);
      float curb = __fadd_rn(__fadd_rn(S0b[r], S1b[r]), bias2b);
      m2a[r] = __fadd_rn(__fmul_rn(0.95f, m2a[r]), cura);
      float sa = (m2a[r] > 1.0f) ? 1.0f : 0.0f;
      m2a[r] = __fsub_rn(m2a[r], sa);
      sl[(rbase + r) * HID + j1] = sa;
      m2b[r] = __fadd_rn(__fmul_rn(0.95f, m2b[r]), curb);
      float sb = (m2b[r] > 1.0f) ? 1.0f : 0.0f;
      m2b[r] = __fsub_rn(m2b[r], sb);
      sl[(rbase + r) * HID + j2] = sb;
    }
    __syncthreads();

#pragma unroll
    for (int r = 0; r < RPTB; ++r) { S0a[r] = 0.f; S0b[r] = 0.f; S1a[r] = 0.f; S1b[r] = 0.f; }
    gemm_f32<HID / 4>(sl, rbase, w3a, w3b, 0, KC4, S0a, S0b);
    gemm_f32<HID / 4>(sl, rbase, w3a, w3b, KC4, HID / 4, S1a, S1b);
    __syncthreads();
#pragma unroll
    for (int r = 0; r < RPTB; ++r) {
      float cura = __fadd_rn(__fadd_rn(S0a[r], S1a[r]), bias3a);
      float curb = __fadd_rn(__fadd_rn(S0b[r], S1b[r]), bias3b);
      m3a[r] = __fadd_rn(__fmul_rn(0.95f, m3a[r]), cura);
      float sa = (m3a[r] > 1.0f) ? 1.0f : 0.0f;
      m3a[r] = __fsub_rn(m3a[r], sa);
      sca[r] = __fadd_rn(sca[r], sa);
      m3b[r] = __fadd_rn(__fmul_rn(0.95f, m3b[r]), curb);
      float sb = (m3b[r] > 1.0f) ? 1.0f : 0.0f;
      m3b[r] = __fsub_rn(m3b[r], sb);
      scb[r] = __fadd_rn(scb[r], sb);
    }
  }

#pragma unroll
  for (int r = 0; r < RPTB; ++r) {
    sl[(rbase + r) * HID + j1] = sca[r] * 0.125f;
    sl[(rbase + r) * HID + j2] = scb[r] * 0.125f;
  }
  __syncthreads();

  if (is_value == 0) {
    if (tid < ROWS * 6) {
      int r = tid / 6, k = tid % 6;
      const float* wr = Wh + (size_t)k * HID;
      float S0 = 0.f, S1 = 0.f;
      for (int i = 0; i < 4 * KC4; ++i)   S0 = fmaf(sl[r * HID + i], wr[i], S0);
      for (int i = 4 * KC4; i < HID; ++i) S1 = fmaf(sl[r * HID + i], wr[i], S1);
      out[(size_t)(r0 + r) * 6 + k] = __fadd_rn(__fadd_rn(S0, S1), bh[k]);
      out[(size_t)B * 6 + (size_t)(r0 + r) * 6 + k] = log_std[k];
    }
  } else {
    if (tid < ROWS) {
      int r = tid;
      float S0 = 0.f, S1 = 0.f;
      for (int i = 0; i < 4 * KC4; ++i)   S0 = fmaf(sl[r * HID + i], Wh[i], S0);
      for (int i = 4 * KC4; i < HID; ++i) S1 = fmaf(sl[r * HID + i], Wh[i], S1);
      out[(size_t)B * 12 + (size_t)(r0 + r)] = __fadd_rn(__fadd_rn(S0, S1), bh[0]);
    }
  }
}

extern "C" void kernel_launch(void* const* d_in, const int* in_sizes, int n_in,
                              void* d_out, int out_size, void* d_ws, size_t ws_size,
                              hipStream_t stream) {
  const float* obs = (const float*)d_in[0];
  const float* pw1 = (const float*)d_in[1];  const float* pb1 = (const float*)d_in[2];
  const float* pw2 = (const float*)d_in[3];  const float* pb2 = (const float*)d_in[4];
  const float* pw3 = (const float*)d_in[5];  const float* pb3 = (const float*)d_in[6];
  const float* aw  = (const float*)d_in[7];  const float* ab  = (const float*)d_in[8];
  const float* vw1 = (const float*)d_in[9];  const float* vb1 = (const float*)d_in[10];
  const float* vw2 = (const float*)d_in[11]; const float* vb2 = (const float*)d_in[12];
  const float* vw3 = (const float*)d_in[13]; const float* vb3 = (const float*)d_in[14];
  const float* hw  = (const float*)d_in[15]; const float* hb  = (const float*)d_in[16];
  const float* lsd = (const float*)d_in[17];
  float* out = (float*)d_out;

  const int B  = in_sizes[0] / IN_DIM;
  const int nb = B / ROWS;

  const size_t need = (size_t)(IN_DIM * HID + 2 * HID * HID) * 2 * sizeof(float);
  if (ws_size >= need && (nb & 3) == 0) {
    float* w = (float*)d_ws;
    float* pP1 = w;
    float* pP2 = w + 131072;
    float* pP3 = w + 393216;
    float* vP1 = w + 655360;
    float* vP2 = w + 786432;
    float* vP3 = w + 1048576;
    wpack4<<<dim3(IN_DIM / 32, 16), 256, 0, stream>>>(pw1, pP1, IN_DIM);
    wpack4<<<dim3(HID / 32, 16),    256, 0, stream>>>(pw2, pP2, HID);
    wpack4<<<dim3(HID / 32, 16),    256, 0, stream>>>(pw3, pP3, HID);
    wpack4<<<dim3(IN_DIM / 32, 16), 256, 0, stream>>>(vw1, vP1, IN_DIM);
    wpack4<<<dim3(HID / 32, 16),    256, 0, stream>>>(vw2, vP2, HID);
    wpack4<<<dim3(HID / 32, 16),    256, 0, stream>>>(vw3, vP3, HID);
    snn_net<<<2 * nb, NTHR, 0, stream>>>(obs,
        (const float4*)pP1, pb1, (const float4*)pP2, pb2, (const float4*)pP3, pb3, aw, ab,
        (const float4*)vP1, vb1, (const float4*)vP2, vb2, (const float4*)vP3, vb3, hw, hb,
        lsd, out, B);
  } else {
    dim3 grid(nb, 2);
    snn_net_base<<<grid, NTHRB, 0, stream>>>(obs,
        pw1, pb1, pw2, pb2, pw3, pb3, aw, ab,
        vw1, vb1, vw2, vb2, vw3, vb3, hw, hb,
        lsd, out, B);
  }
}

// Round 15
// 2444.842 us; speedup vs baseline: 1.3231x; 1.3231x over previous
//
#include <hip/hip_runtime.h>
#include <cstdint>
#include <cstddef>

#define IN_DIM 256
#define HID    512
#define TSTEPS 8
#define ROWS   8       // batch rows per block (small blocks -> 4 blocks/CU)
#define NTHR   256     // 128 col-slots x 2 row-groups
#define RPT    4       // rows per thread
#define KC4    96      // OpenBLAS kc=384 boundary in floats/4 (head loops)

// ---- pack: Pf[(k*128+jj)*4 + c] = W[jj+128c][k]  (round-9 proven layout)
__global__ void wpack4(const float* __restrict__ W, float* __restrict__ Pf, int K) {
  __shared__ float tl[32][33];
  const int k0 = blockIdx.x * 32;
  const int j0 = blockIdx.y * 32;
  const int tx = threadIdx.x & 31, ty = threadIdx.x >> 5;
#pragma unroll
  for (int i = 0; i < 32; i += 8)
    tl[ty + i][tx] = W[(size_t)(j0 + ty + i) * K + (k0 + tx)];
  __syncthreads();
  const int c = j0 >> 7;
  const int jjb = j0 & 127;
#pragma unroll
  for (int i = 0; i < 32; i += 8) {
    int k = k0 + ty + i;
    Pf[((size_t)k * 128 + (jjb + tx)) * 4 + c] = tl[tx][ty + i];
  }
}

// ---- dense f32-obs GEMM (layer 1, K=256 single panel) — proven
__device__ __forceinline__ void gemm_obs(const float* __restrict__ obsT,
                                         int rbase, const float4* __restrict__ P,
                                         int j1, float (&A)[RPT][4]) {
#pragma unroll 1
  for (int i4 = 0; i4 < IN_DIM / 4; ++i4) {
    const float4* wp = P + ((size_t)i4 << 9) + j1;
    float4 w0 = wp[0], w1 = wp[128], w2 = wp[256], w3 = wp[384];
#pragma unroll
    for (int r = 0; r < RPT; ++r) {
      float4 o = *reinterpret_cast<const float4*>(obsT + ((rbase + r) << 8) + (i4 << 2));
      float a0 = A[r][0], a1 = A[r][1], a2 = A[r][2], a3 = A[r][3];
      a0 = fmaf(o.x, w0.x, a0); a1 = fmaf(o.x, w0.y, a1); a2 = fmaf(o.x, w0.z, a2); a3 = fmaf(o.x, w0.w, a3);
      a0 = fmaf(o.y, w1.x, a0); a1 = fmaf(o.y, w1.y, a1); a2 = fmaf(o.y, w1.z, a2); a3 = fmaf(o.y, w1.w, a3);
      a0 = fmaf(o.z, w2.x, a0); a1 = fmaf(o.z, w2.y, a1); a2 = fmaf(o.z, w2.z, a2); a3 = fmaf(o.z, w2.w, a3);
      a0 = fmaf(o.w, w3.x, a0); a1 = fmaf(o.w, w3.y, a1); a2 = fmaf(o.w, w3.z, a2); a3 = fmaf(o.w, w3.w, a3);
      A[r][0] = a0; A[r][1] = a1; A[r][2] = a2; A[r][3] = a3;
    }
  }
}

// ---- sparse helpers (round-10 proven): 8-entry chunk, k wave-uniform
__device__ __forceinline__ void loadchunk(float4 (&w)[8], uint4 kw,
                                          const float4* __restrict__ P, int j1) {
  int s0 = __builtin_amdgcn_readfirstlane((int)kw.x);
  int s1 = __builtin_amdgcn_readfirstlane((int)kw.y);
  int s2 = __builtin_amdgcn_readfirstlane((int)kw.z);
  int s3 = __builtin_amdgcn_readfirstlane((int)kw.w);
  w[0] = P[((s0 & 0xffff) << 7) + j1];
  w[1] = P[((s0 >> 16) << 7) + j1];
  w[2] = P[((s1 & 0xffff) << 7) + j1];
  w[3] = P[((s1 >> 16) << 7) + j1];
  w[4] = P[((s2 & 0xffff) << 7) + j1];
  w[5] = P[((s2 >> 16) << 7) + j1];
  w[6] = P[((s3 & 0xffff) << 7) + j1];
  w[7] = P[((s3 >> 16) << 7) + j1];
}

__device__ __forceinline__ void consume8(const float4 (&w)[8], float (&A)[4]) {
#pragma unroll
  for (int kk = 0; kk < 8; ++kk) {
    A[0] = __fadd_rn(A[0], w[kk].x);
    A[1] = __fadd_rn(A[1], w[kk].y);
    A[2] = __fadd_rn(A[2], w[kk].z);
    A[3] = __fadd_rn(A[3], w[kk].w);
  }
}

__device__ __forceinline__ void panel(const unsigned short* __restrict__ lp, int n,
                                      const float4* __restrict__ P, int j1,
                                      float (&A)[4]) {
  const uint4* kp = reinterpret_cast<const uint4*>(lp);
  int C = n >> 3;
  float4 wA[8], wB[8];
  if (C > 0) {
    loadchunk(wA, kp[0], P, j1);
    int ci = 0;
#pragma unroll 1
    for (; ci + 2 <= C; ci += 2) {
      loadchunk(wB, kp[ci + 1], P, j1);
      consume8(wA, A);
      if (ci + 2 < C) loadchunk(wA, kp[ci + 2], P, j1);
      consume8(wB, A);
    }
    if (ci < C) consume8(wA, A);
  }
#pragma unroll 1
  for (int e = C << 3; e < n; ++e) {
    int k = lp[e];
    float4 wt = P[(k << 7) + j1];
    A[0] = __fadd_rn(A[0], wt.x);
    A[1] = __fadd_rn(A[1], wt.y);
    A[2] = __fadd_rn(A[2], wt.z);
    A[3] = __fadd_rn(A[3], wt.w);
  }
}

// (256,2): 128-VGPR cap (live set ~120, round-13-verified no spill at 128).
// 16.4KB LDS + 128 VGPR -> up to 4 blocks (16 waves) per CU.
__launch_bounds__(NTHR, 2)
__global__ void snn_net(const float* __restrict__ obs,
                        const float4* __restrict__ pP1, const float* __restrict__ pb1_,
                        const float4* __restrict__ pP2, const float* __restrict__ pb2_,
                        const float4* __restrict__ pP3, const float* __restrict__ pb3_,
                        const float* __restrict__ paw, const float* __restrict__ pab,
                        const float4* __restrict__ vP1, const float* __restrict__ vb1_,
                        const float4* __restrict__ vP2, const float* __restrict__ vb2_,
                        const float4* __restrict__ vP3, const float* __restrict__ vb3_,
                        const float* __restrict__ vhw, const float* __restrict__ vhb,
                        const float* __restrict__ log_std,
                        float* __restrict__ out, int B) {
  const int bid = blockIdx.x;
  const int xcd = bid & 7;
  const int is_value = xcd >> 2;
  const int tile = (bid >> 3) * 4 + (xcd & 3);
  const float4* P1 = is_value ? vP1 : pP1;  const float* b1 = is_value ? vb1_ : pb1_;
  const float4* P2 = is_value ? vP2 : pP2;  const float* b2 = is_value ? vb2_ : pb2_;
  const float4* P3 = is_value ? vP3 : pP3;  const float* b3 = is_value ? vb3_ : pb3_;
  const float* Wh  = is_value ? vhw : paw;  const float* bh = is_value ? vhb : pab;

  // LDS 16384 B:
  //   start: obsT f32 [0,8K)
  //   loop:  spk u8 [0,4K); cnts [4096,4160); lists u16 [4224,12416)
  //   end:   meanT f32 [0,16K)
  __shared__ __align__(16) unsigned char lraw[16384];
  float* obsT = (float*)lraw;
  float* meanT = (float*)lraw;
  unsigned char* spk = lraw;
  unsigned* cnts = (unsigned*)(lraw + 4096);
  unsigned short* listb = (unsigned short*)(lraw + 4224);

  const int tid = threadIdx.x;
  const int lane = tid & 63;
  const int wid = tid >> 6;             // 0..3
  const int j1 = tid & 127;
  const int rbase = (tid >> 7) * RPT;   // 0 or 4
  const int r0 = tile * ROWS;

  // ---- stage obs tile
  {
    const float4* src = reinterpret_cast<const float4*>(obs + (size_t)r0 * IN_DIM);
    float4* dst = reinterpret_cast<float4*>(obsT);
    for (int e = tid; e < ROWS * IN_DIM / 4; e += NTHR) dst[e] = src[e];
  }
  __syncthreads();

  // ---- layer-1 currents in registers (K=256 single BLAS panel, bias AFTER sum)
  float c1v[RPT][4];
  {
    float Sa[RPT][4];
#pragma unroll
    for (int r = 0; r < RPT; ++r)
#pragma unroll
      for (int c = 0; c < 4; ++c) Sa[r][c] = 0.f;
    gemm_obs(obsT, rbase, P1, j1, Sa);
    const float bb0 = b1[j1], bb1 = b1[j1 + 128], bb2 = b1[j1 + 256], bb3 = b1[j1 + 384];
#pragma unroll
    for (int r = 0; r < RPT; ++r) {
      c1v[r][0] = __fadd_rn(Sa[r][0], bb0);
      c1v[r][1] = __fadd_rn(Sa[r][1], bb1);
      c1v[r][2] = __fadd_rn(Sa[r][2], bb2);
      c1v[r][3] = __fadd_rn(Sa[r][3], bb3);
    }
  }
  __syncthreads();  // obs reads done; spk buffer may alias obsT now

  float m1[RPT][4], m2[RPT][4], m3[RPT][4];
  unsigned cnt32[2] = {0u, 0u};
#pragma unroll
  for (int r = 0; r < RPT; ++r)
#pragma unroll
    for (int c = 0; c < 4; ++c) { m1[r][c] = 0.f; m2[r][c] = 0.f; m3[r][c] = 0.f; }

  const float bias2[4] = { b2[j1], b2[j1 + 128], b2[j1 + 256], b2[j1 + 384] };
  const float bias3[4] = { b3[j1], b3[j1 + 128], b3[j1 + 256], b3[j1 + 384] };

  // ---- list builder (round-10 central form): wave handles rows 2*wid, 2*wid+1
  auto build = [&]() {
#pragma unroll
    for (int rr = 0; rr < 2; ++rr) {
      int row = wid * 2 + rr;
      unsigned long long b8 =
          *reinterpret_cast<const unsigned long long*>(spk + (row << 9) + (lane << 3));
      int cnt = __popcll(b8);       // spike bytes are 0/1
      int S = cnt;
#pragma unroll
      for (int off = 1; off < 64; off <<= 1) {
        int tv = __shfl_up(S, off);
        if (lane >= off) S += tv;
      }
      int total = __shfl(S, 63);
      int lowtot = __shfl(S, 47);   // k < 384 <=> lane < 48
      int excl = S - cnt;
      unsigned short* lrow = listb + (row << 9);
      int pos = (lane < 48) ? excl : (384 + excl - lowtot);
#pragma unroll
      for (int b = 0; b < 8; ++b) {
        if ((b8 >> (8 * b)) & 1ull) {
          lrow[pos] = (unsigned short)((lane << 3) + b);
          ++pos;
        }
      }
      if (lane == 0) {
        cnts[row * 2] = (unsigned)lowtot;
        cnts[row * 2 + 1] = (unsigned)total;
      }
    }
  };

#pragma unroll 1
  for (int t = 0; t < TSTEPS; ++t) {
    // ---- LIF layer 1 (numpy order: mul, add, cmp, sub) -> spikes u8 -> spk
#pragma unroll
    for (int r = 0; r < RPT; ++r)
#pragma unroll
      for (int c = 0; c < 4; ++c) {
        m1[r][c] = __fadd_rn(__fmul_rn(0.95f, m1[r][c]), c1v[r][c]);
        bool f = m1[r][c] > 1.0f;
        m1[r][c] = __fsub_rn(m1[r][c], f ? 1.0f : 0.0f);
        spk[((rbase + r) << 9) + j1 + (c << 7)] = f ? 1 : 0;
      }
    __syncthreads();   // spk(l1) ready; everyone past prior gemm3 list reads
    build();
    __syncthreads();   // list(l1) ready

    // ---- layer 2: sparse panels (kc=384 split), RN(S0+S1)+bias -> spk (reuse)
#pragma unroll 1
    for (int r = 0; r < RPT; ++r) {
      int row = rbase + r;
      int nlow = (int)cnts[row * 2];
      int ntot = (int)cnts[row * 2 + 1];
      const unsigned short* lrow = listb + (row << 9);
      float A0[4] = {0.f, 0.f, 0.f, 0.f}, A1[4] = {0.f, 0.f, 0.f, 0.f};
      panel(lrow, nlow, P2, j1, A0);
      panel(lrow + 384, ntot - nlow, P2, j1, A1);
#pragma unroll
      for (int c = 0; c < 4; ++c) {
        float cur = __fadd_rn(__fadd_rn(A0[c], A1[c]), bias2[c]);
        m2[r][c] = __fadd_rn(__fmul_rn(0.95f, m2[r][c]), cur);
        bool f = m2[r][c] > 1.0f;
        m2[r][c] = __fsub_rn(m2[r][c], f ? 1.0f : 0.0f);
        spk[(row << 9) + j1 + (c << 7)] = f ? 1 : 0;   // list already consumed? no:
        // safe: spk and listb are disjoint; list reads continue from listb only.
      }
    }
    __syncthreads();   // spk(l2) ready; all gemm2 list reads done
    build();
    __syncthreads();   // list(l2) ready

    // ---- layer 3: sparse panels; packed spike counts
#pragma unroll 1
    for (int r = 0; r < RPT; ++r) {
      int row = rbase + r;
      int nlow = (int)cnts[row * 2];
      int ntot = (int)cnts[row * 2 + 1];
      const unsigned short* lrow = listb + (row << 9);
      float A0[4] = {0.f, 0.f, 0.f, 0.f}, A1[4] = {0.f, 0.f, 0.f, 0.f};
      panel(lrow, nlow, P3, j1, A0);
      panel(lrow + 384, ntot - nlow, P3, j1, A1);
#pragma unroll
      for (int c = 0; c < 4; ++c) {
        float cur = __fadd_rn(__fadd_rn(A0[c], A1[c]), bias3[c]);
        m3[r][c] = __fadd_rn(__fmul_rn(0.95f, m3[r][c]), cur);
        bool f = m3[r][c] > 1.0f;
        m3[r][c] = __fsub_rn(m3[r][c], f ? 1.0f : 0.0f);
        cnt32[r >> 1] += f ? (1u << (((r & 1) * 4 + c) * 4)) : 0u;
      }
    }
    // next t's first barrier fences the spk/list overwrites
  }
  __syncthreads();

  // ---- mean spikes (count/8 exact)
#pragma unroll
  for (int r = 0; r < RPT; ++r)
#pragma unroll
    for (int c = 0; c < 4; ++c)
      meanT[(rbase + r) * HID + j1 + (c << 7)] =
          (float)((cnt32[r >> 1] >> (((r & 1) * 4 + c) * 4)) & 15u) * 0.125f;
  __syncthreads();

  // ---- heads (BLAS two-panel, kc=384)
  if (is_value == 0) {
    if (tid < ROWS * 6) {
      int r = tid / 6, k = tid % 6;
      const float* wr = Wh + (size_t)k * HID;
      float S0h = 0.f, S1h = 0.f;
      for (int i = 0; i < 4 * KC4; ++i)   S0h = fmaf(meanT[r * HID + i], wr[i], S0h);
      for (int i = 4 * KC4; i < HID; ++i) S1h = fmaf(meanT[r * HID + i], wr[i], S1h);
      out[(size_t)(r0 + r) * 6 + k] = __fadd_rn(__fadd_rn(S0h, S1h), bh[k]);
      out[(size_t)B * 6 + (size_t)(r0 + r) * 6 + k] = log_std[k];
    }
  } else {
    if (tid < ROWS) {
      int r = tid;
      float S0h = 0.f, S1h = 0.f;
      for (int i = 0; i < 4 * KC4; ++i)   S0h = fmaf(meanT[r * HID + i], Wh[i], S0h);
      for (int i = 4 * KC4; i < HID; ++i) S1h = fmaf(meanT[r * HID + i], Wh[i], S1h);
      out[(size_t)B * 12 + (size_t)(r0 + r)] = __fadd_rn(__fadd_rn(S0h, S1h), bh[0]);
    }
  }
}

// ---------------- fallback (round-3 kernel, proven) ----------------
#define NTHRB 512
#define RPTB  8
#define ROWSB 16
template<int PITCH4>
__device__ __forceinline__ void gemm_f32(const float* __restrict__ sl, int rbase,
                                         const float4* __restrict__ wra,
                                         const float4* __restrict__ wrb,
                                         int i4begin, int i4end,
                                         float a0[RPTB], float a1[RPTB]) {
  const float4* slv = reinterpret_cast<const float4*>(sl);
  for (int i4 = i4begin; i4 < i4end; ++i4) {
    float4 wa = wra[i4];
    float4 wb = wrb[i4];
#pragma unroll
    for (int r = 0; r < RPTB; ++r) {
      float4 s = slv[(rbase + r) * PITCH4 + i4];
      a0[r] = fmaf(s.w, wa.w, fmaf(s.z, wa.z, fmaf(s.y, wa.y, fmaf(s.x, wa.x, a0[r]))));
      a1[r] = fmaf(s.w, wb.w, fmaf(s.z, wb.z, fmaf(s.y, wb.y, fmaf(s.x, wb.x, a1[r]))));
    }
  }
}

__launch_bounds__(NTHRB, 2)
__global__ void snn_net_base(const float* __restrict__ obs,
                             const float* __restrict__ pW1, const float* __restrict__ pb1_,
                             const float* __restrict__ pW2, const float* __restrict__ pb2_,
                             const float* __restrict__ pW3, const float* __restrict__ pb3_,
                             const float* __restrict__ paw, const float* __restrict__ pab,
                             const float* __restrict__ vW1, const float* __restrict__ vb1_,
                             const float* __restrict__ vW2, const float* __restrict__ vb2_,
                             const float* __restrict__ vW3, const float* __restrict__ vb3_,
                             const float* __restrict__ vhw, const float* __restrict__ vhb,
                             const float* __restrict__ log_std,
                             float* __restrict__ out, int B) {
  const int is_value = blockIdx.y;
  const float* W1 = is_value ? vW1 : pW1;  const float* b1 = is_value ? vb1_ : pb1_;
  const float* W2 = is_value ? vW2 : pW2;  const float* b2 = is_value ? vb2_ : pb2_;
  const float* W3 = is_value ? vW3 : pW3;  const float* b3 = is_value ? vb3_ : pb3_;
  const float* Wh = is_value ? vhw : paw;  const float* bh = is_value ? vhb : pab;

  __shared__ float sl[ROWSB * HID];
  const int tid = threadIdx.x;
  const int r0 = blockIdx.x * ROWSB;
  const int j1 = tid & 255, j2 = j1 + 256;
  const int rbase = (tid >> 8) * RPTB;

  for (int e = tid; e < ROWSB * IN_DIM; e += NTHRB)
    sl[e] = obs[(size_t)r0 * IN_DIM + e];
  __syncthreads();

  float c1a[RPTB], c1b[RPTB];
  {
    float Sa[RPTB], Sb[RPTB];
#pragma unroll
    for (int r = 0; r < RPTB; ++r) { Sa[r] = 0.f; Sb[r] = 0.f; }
    gemm_f32<IN_DIM / 4>(sl, rbase,
        reinterpret_cast<const float4*>(W1 + (size_t)j1 * IN_DIM),
        reinterpret_cast<const float4*>(W1 + (size_t)j2 * IN_DIM),
        0, IN_DIM / 4, Sa, Sb);
    const float ba = b1[j1], bb = b1[j2];
#pragma unroll
    for (int r = 0; r < RPTB; ++r) {
      c1a[r] = __fadd_rn(Sa[r], ba);
      c1b[r] = __fadd_rn(Sb[r], bb);
    }
  }
  __syncthreads();

  float m1a[RPTB], m1b[RPTB], m2a[RPTB], m2b[RPTB], m3a[RPTB], m3b[RPTB];
  float sca[RPTB], scb[RPTB];
#pragma unroll
  for (int r = 0; r < RPTB; ++r) {
    m1a[r] = 0.f; m1b[r] = 0.f; m2a[r] = 0.f; m2b[r] = 0.f;
    m3a[r] = 0.f; m3b[r] = 0.f; sca[r] = 0.f; scb[r] = 0.f;
  }

  const float4* w2a = reinterpret_cast<const float4*>(W2 + (size_t)j1 * HID);
  const float4* w2b = reinterpret_cast<const float4*>(W2 + (size_t)j2 * HID);
  const float4* w3a = reinterpret_cast<const float4*>(W3 + (size_t)j1 * HID);
  const float4* w3b = reinterpret_cast<const float4*>(W3 + (size_t)j2 * HID);
  const float bias2a = b2[j1], bias2b = b2[j2];
  const float bias3a = b3[j1], bias3b = b3[j2];

  for (int t = 0; t < TSTEPS; ++t) {
#pragma unroll
    for (int r = 0; r < RPTB; ++r) {
      m1a[r] = __fadd_rn(__fmul_rn(0.95f, m1a[r]), c1a[r]);
      float sa = (m1a[r] > 1.0f) ? 1.0f : 0.0f;
      m1a[r] = __fsub_rn(m1a[r], sa);
      sl[(rbase + r) * HID + j1] = sa;
      m1b[r] = __fadd_rn(__fmul_rn(0.95f, m1b[r]), c1b[r]);
      float sb = (m1b[r] > 1.0f) ? 1.0f : 0.0f;
      m1b[r] = __fsub_rn(m1b[r], sb);
      sl[(rbase + r) * HID + j2] = sb;
    }
    __syncthreads();

    float S0a[RPTB], S0b[RPTB], S1a[RPTB], S1b[RPTB];
#pragma unroll
    for (int r = 0; r < RPTB; ++r) { S0a[r] = 0.f; S0b[r] = 0.f; S1a[r] = 0.f; S1b[r] = 0.f; }
    gemm_f32<HID / 4>(sl, rbase, w2a, w2b, 0, KC4, S0a, S0b);
    gemm_f32<HID / 4>(sl, rbase, w2a, w2b, KC4, HID / 4, S1a, S1b);
    __syncthreads();
#pragma unroll
    for (int r = 0; r < RPTB; ++r) {
      float cura = __fadd_rn(__fadd_rn(S0a[r], S1a[r]), bias2a);
      float curb = __fadd_rn(__fadd_rn(S0b[r], S1b[r]), bias2b);
      m2a[r] = __fadd_rn(__fmul_rn(0.95f, m2a[r]), cura);
      float sa = (m2a[r] > 1.0f) ? 1.0f : 0.0f;
      m2a[r] = __fsub_rn(m2a[r], sa);
      sl[(rbase + r) * HID + j1] = sa;
      m2b[r] = __fadd_rn(__fmul_rn(0.95f, m2b[r]), curb);
      float sb = (m2b[r] > 1.0f) ? 1.0f : 0.0f;
      m2b[r] = __fsub_rn(m2b[r], sb);
      sl[(rbase + r) * HID + j2] = sb;
    }
    __syncthreads();

#pragma unroll
    for (int r = 0; r < RPTB; ++r) { S0a[r] = 0.f; S0b[r] = 0.f; S1a[r] = 0.f; S1b[r] = 0.f; }
    gemm_f32<HID / 4>(sl, rbase, w3a, w3b, 0, KC4, S0a, S0b);
    gemm_f32<HID / 4>(sl, rbase, w3a, w3b, KC4, HID / 4, S1a, S1b);
    __syncthreads();
#pragma unroll
    for (int r = 0; r < RPTB; ++r) {
      float cura = __fadd_rn(__fadd_rn(S0a[r], S1a[r]), bias3a);
      float curb = __fadd_rn(__fadd_rn(S0b[r], S1b[r]), bias3b);
      m3a[r] = __fadd_rn(__fmul_rn(0.95f, m3a[r]), cura);
      float sa = (m3a[r] > 1.0f) ? 1.0f : 0.0f;
      m3a[r] = __fsub_rn(m3a[r], sa);
      sca[r] = __fadd_rn(sca[r], sa);
      m3b[r] = __fadd_rn(__fmul_rn(0.95f, m3b[r]), curb);
      float sb = (m3b[r] > 1.0f) ? 1.0f : 0.0f;
      m3b[r] = __fsub_rn(m3b[r], sb);
      scb[r] = __fadd_rn(scb[r], sb);
    }
  }

#pragma unroll
  for (int r = 0; r < RPTB; ++r) {
    sl[(rbase + r) * HID + j1] = sca[r] * 0.125f;
    sl[(rbase + r) * HID + j2] = scb[r] * 0.125f;
  }
  __syncthreads();

  if (is_value == 0) {
    if (tid < ROWSB * 6) {
      int r = tid / 6, k = tid % 6;
      const float* wr = Wh + (size_t)k * HID;
      float S0 = 0.f, S1 = 0.f;
      for (int i = 0; i < 4 * KC4; ++i)   S0 = fmaf(sl[r * HID + i], wr[i], S0);
      for (int i = 4 * KC4; i < HID; ++i) S1 = fmaf(sl[r * HID + i], wr[i], S1);
      out[(size_t)(r0 + r) * 6 + k] = __fadd_rn(__fadd_rn(S0, S1), bh[k]);
      out[(size_t)B * 6 + (size_t)(r0 + r) * 6 + k] = log_std[k];
    }
  } else {
    if (tid < ROWSB) {
      int r = tid;
      float S0 = 0.f, S1 = 0.f;
      for (int i = 0; i < 4 * KC4; ++i)   S0 = fmaf(sl[r * HID + i], Wh[i], S0);
      for (int i = 4 * KC4; i < HID; ++i) S1 = fmaf(sl[r * HID + i], Wh[i], S1);
      out[(size_t)B * 12 + (size_t)(r0 + r)] = __fadd_rn(__fadd_rn(S0, S1), bh[0]);
    }
  }
}

extern "C" void kernel_launch(void* const* d_in, const int* in_sizes, int n_in,
                              void* d_out, int out_size, void* d_ws, size_t ws_size,
                              hipStream_t stream) {
  const float* obs = (const float*)d_in[0];
  const float* pw1 = (const float*)d_in[1];  const float* pb1 = (const float*)d_in[2];
  const float* pw2 = (const float*)d_in[3];  const float* pb2 = (const float*)d_in[4];
  const float* pw3 = (const float*)d_in[5];  const float* pb3 = (const float*)d_in[6];
  const float* aw  = (const float*)d_in[7];  const float* ab  = (const float*)d_in[8];
  const float* vw1 = (const float*)d_in[9];  const float* vb1 = (const float*)d_in[10];
  const float* vw2 = (const float*)d_in[11]; const float* vb2 = (const float*)d_in[12];
  const float* vw3 = (const float*)d_in[13]; const float* vb3 = (const float*)d_in[14];
  const float* hw  = (const float*)d_in[15]; const float* hb  = (const float*)d_in[16];
  const float* lsd = (const float*)d_in[17];
  float* out = (float*)d_out;

  const int B  = in_sizes[0] / IN_DIM;
  const int nb = B / ROWS;     // 8-row tiles for the fast path

  const size_t need = (size_t)(IN_DIM * HID + 2 * HID * HID) * 2 * sizeof(float);
  if (ws_size >= need && (nb & 3) == 0) {
    float* w = (float*)d_ws;
    float* pP1 = w;
    float* pP2 = w + 131072;
    float* pP3 = w + 393216;
    float* vP1 = w + 655360;
    float* vP2 = w + 786432;
    float* vP3 = w + 1048576;
    wpack4<<<dim3(IN_DIM / 32, 16), 256, 0, stream>>>(pw1, pP1, IN_DIM);
    wpack4<<<dim3(HID / 32, 16),    256, 0, stream>>>(pw2, pP2, HID);
    wpack4<<<dim3(HID / 32, 16),    256, 0, stream>>>(pw3, pP3, HID);
    wpack4<<<dim3(IN_DIM / 32, 16), 256, 0, stream>>>(vw1, vP1, IN_DIM);
    wpack4<<<dim3(HID / 32, 16),    256, 0, stream>>>(vw2, vP2, HID);
    wpack4<<<dim3(HID / 32, 16),    256, 0, stream>>>(vw3, vP3, HID);
    snn_net<<<2 * nb, NTHR, 0, stream>>>(obs,
        (const float4*)pP1, pb1, (const float4*)pP2, pb2, (const float4*)pP3, pb3, aw, ab,
        (const float4*)vP1, vb1, (const float4*)vP2, vb2, (const float4*)vP3, vb3, hw, hb,
        lsd, out, B);
  } else {
    dim3 grid(B / ROWSB, 2);
    snn_net_base<<<grid, NTHRB, 0, stream>>>(obs,
        pw1, pb1, pw2, pb2, pw3, pb3, aw, ab,
        vw1, vb1, vw2, vb2, vw3, vb3, hw, hb,
        lsd, out, B);
  }
}